// Round 2
// baseline (159.852 us; speedup 1.0000x reference)
//
#include <hip/hip_runtime.h>

#define NP 4096
#define NSLAB 64
#define ZSPAN 12        // 12/64 = 0.1875 >= 0.1866 max interaction distance
#define MAXCHUNK 16     // supports up to 128 particles per slab (mean 64, sd ~8)
#define TJ 512
#define EPS_K 1e-12f

// ---------- prep: nd = data / density ----------
__global__ void k_nd(const float* __restrict__ data, const float* __restrict__ density,
                     float* __restrict__ nd, int total) {
    int e = blockIdx.x * 256 + threadIdx.x;
    if (e < total) nd[e] = data[e] / density[e >> 4];
}

// ---------- prep: histogram of z-slabs ----------
__global__ void k_hist(const float* __restrict__ locs, int* __restrict__ cnt, int totalP) {
    int i = blockIdx.x * 256 + threadIdx.x;
    if (i < totalP) {
        float z = locs[i * 3 + 2];
        int c = min(max((int)(z * 64.0f), 0), 63);
        atomicAdd(&cnt[(i >> 12) * NSLAB + c], 1);   // i>>12 == batch (NP=4096)
    }
}

// ---------- prep: exclusive scan of 64 bins per batch (1 wave per batch) ----------
__global__ void k_scan(const int* __restrict__ cnt, int* __restrict__ off, int B) {
    int lane = threadIdx.x & 63;
    int b = threadIdx.x >> 6;
    if (b >= B) return;
    int incl = cnt[b * NSLAB + lane];
    for (int d = 1; d < 64; d <<= 1) {
        int o = __shfl_up(incl, d, 64);
        if (lane >= d) incl += o;
    }
    off[b * (NSLAB + 1) + lane + 1] = incl;
    if (lane == 0) off[b * (NSLAB + 1)] = 0;
}

// ---------- prep: deterministic stable rank + scatter (block = one slab) ----------
__global__ __launch_bounds__(256) void k_rank(const float* __restrict__ locs,
                                              const int* __restrict__ off,
                                              int* __restrict__ list) {
    int b = blockIdx.x / NSLAB;
    int s = blockIdx.x % NSLAB;
    const float* lz = locs + (size_t)b * NP * 3;
    __shared__ int wtot[4];
    int base = off[b * (NSLAB + 1) + s];
    int running = 0;
    int tid = threadIdx.x, lane = tid & 63, w = tid >> 6;
    for (int chunk = 0; chunk < NP; chunk += 256) {
        int i = chunk + tid;
        float z = lz[i * 3 + 2];
        int c = min(max((int)(z * 64.0f), 0), 63);
        bool match = (c == s);
        unsigned long long m = __ballot(match);
        int pre = __popcll(m & ((1ull << lane) - 1ull));
        if (lane == 0) wtot[w] = (int)__popcll(m);
        __syncthreads();
        int bp = 0, tot = 0;
        for (int ww = 0; ww < 4; ++ww) { if (ww < w) bp += wtot[ww]; tot += wtot[ww]; }
        if (match) list[b * NP + base + running + bp + pre] = i;
        running += tot;
        __syncthreads();
    }
}

// ---------- main ----------
__global__ __launch_bounds__(256) void k_main(
    const float* __restrict__ locs, const float* __restrict__ nd,
    const int* __restrict__ off, const int* __restrict__ list,
    const float* __restrict__ weight, const float* __restrict__ bias,
    float* __restrict__ out)
{
    __shared__ float4 s_locs[TJ];
    const int bid = blockIdx.x;
    const int b = bid >> 10;             // NSLAB*MAXCHUNK = 1024 blocks per batch
    const int rem = bid & 1023;
    const int s = rem >> 4;
    const int m = rem & 15;

    const int* off_b = off + b * (NSLAB + 1);
    const int sbeg = off_b[s], send = off_b[s + 1];
    const int pstart = sbeg + m * 8;
    if (pstart >= send) return;          // uniform over block
    const int pcnt = min(8, send - pstart);

    const int tid = threadIdx.x;
    const int p = tid >> 5;
    const int lane = tid & 31;

    const int s0 = max(s - ZSPAN, 0);
    const int s1 = min(s + ZSPAN, NSLAB - 1);
    const int jstart = off_b[s0];
    const int jend = off_b[s1 + 1];

    const float* locs_b = locs + (size_t)b * NP * 3;
    const float* nd_b   = nd   + (size_t)b * NP * 16;
    const int*   list_b = list + b * NP;

    const int ppos = pstart + min(p, pcnt - 1);
    const int orig = list_b[ppos];
    const float lix = locs_b[orig * 3 + 0];
    const float liy = locs_b[orig * 3 + 1];
    const float liz = locs_b[orig * 3 + 2];

    // this lane's kernel-cell center; idle lanes (27..31) get w==0 branchlessly
    float cx, cy, cz;
    {
        int kk = (lane < 27) ? lane : 13;
        cx = lix + (float)(kk / 9       - 1) * 0.05f;
        cy = liy + (float)((kk / 3) % 3 - 1) * 0.05f;
        cz = liz + (float)(kk % 3       - 1) * 0.05f;
        if (lane >= 27) cx = 1e9f;
    }

    float kv[16];
#pragma unroll
    for (int c = 0; c < 16; ++c) kv[c] = 0.f;

    for (int tb = jstart; tb < jend; tb += TJ) {
        __syncthreads();
        for (int t = tid; t < TJ; t += 256) {
            int j = tb + t;
            float4 e;
            if (j < jend) {
                int idx = list_b[j];
                e.x = locs_b[idx * 3 + 0];
                e.y = locs_b[idx * 3 + 1];
                e.z = locs_b[idx * 3 + 2];
                e.w = __int_as_float(idx);
            } else { e.x = 1e9f; e.y = 1e9f; e.z = 1e9f; e.w = 0.f; }
            s_locs[t] = e;
        }
        __syncthreads();

        const int nc = min(TJ, jend - tb);
        const int nb = (nc + 31) >> 5;
        for (int base = 0; base < nb; ++base) {
            const float4 lj = s_locs[(base << 5) + lane];
            // box prefilter: distance to cell cube [-0.05,0.05]^3 dilated by R
            const float ex = fmaxf(fabsf(lix - lj.x) - 0.05f, 0.f);
            const float ey = fmaxf(fabsf(liy - lj.y) - 0.05f, 0.f);
            const float ez = fmaxf(fabsf(liz - lj.z) - 0.05f, 0.f);
            const float bd2 = ex * ex + ey * ey + ez * ez;
            const unsigned long long mball = __ballot(bd2 < 0.01f);
            unsigned int mh = (unsigned int)(mball >> (tid & 32));

            while (mh) {
                const int bit = __ffs(mh) - 1;
                mh &= mh - 1;
                const float4 q = s_locs[(base << 5) + bit];   // uniform per half
                const int idx = __float_as_int(q.w);
                const float4* dp = (const float4*)(nd_b + (size_t)idx * 16);
                const float4 v0 = dp[0], v1 = dp[1], v2 = dp[2], v3 = dp[3];
                const float dx = cx - q.x, dy = cy - q.y, dz = cz - q.z;
                const float d2 = dx * dx + dy * dy + dz * dz;
                const float d = sqrtf(fmaxf(d2, EPS_K));
                float t1 = fmaxf(__builtin_fmaf(d, -10.f, 1.f), 0.f);  // max(1-d/R, 0)
                const float w = t1 * t1 * t1;
                kv[ 0] = fmaf(w, v0.x, kv[ 0]);
                kv[ 1] = fmaf(w, v0.y, kv[ 1]);
                kv[ 2] = fmaf(w, v0.z, kv[ 2]);
                kv[ 3] = fmaf(w, v0.w, kv[ 3]);
                kv[ 4] = fmaf(w, v1.x, kv[ 4]);
                kv[ 5] = fmaf(w, v1.y, kv[ 5]);
                kv[ 6] = fmaf(w, v1.z, kv[ 6]);
                kv[ 7] = fmaf(w, v1.w, kv[ 7]);
                kv[ 8] = fmaf(w, v2.x, kv[ 8]);
                kv[ 9] = fmaf(w, v2.y, kv[ 9]);
                kv[10] = fmaf(w, v2.z, kv[10]);
                kv[11] = fmaf(w, v2.w, kv[11]);
                kv[12] = fmaf(w, v3.x, kv[12]);
                kv[13] = fmaf(w, v3.y, kv[13]);
                kv[14] = fmaf(w, v3.z, kv[14]);
                kv[15] = fmaf(w, v3.w, kv[15]);
            }
        }
    }

    // epilogue: out[o] = bias[o] + sum_k sum_c weight[o,c,k]*kv[k][c]
    const int kk = (lane < 27) ? lane : 26;   // idle lanes: kv==0
    float res = 0.f;
#pragma unroll
    for (int o = 0; o < 16; ++o) {
        float acc = 0.f;
#pragma unroll
        for (int c = 0; c < 16; ++c)
            acc = fmaf(weight[(o * 16 + c) * 27 + kk], kv[c], acc);
#pragma unroll
        for (int d = 16; d >= 1; d >>= 1)
            acc += __shfl_xor(acc, d, 32);
        if (lane == o) res = acc;
    }
    if (p < pcnt && lane < 16)
        out[((size_t)(b * NP + orig)) * 16 + lane] = res + bias[lane];
}

extern "C" void kernel_launch(void* const* d_in, const int* in_sizes, int n_in,
                              void* d_out, int out_size, void* d_ws, size_t ws_size,
                              hipStream_t stream) {
    const float* locs    = (const float*)d_in[0];
    const float* data    = (const float*)d_in[1];
    const float* density = (const float*)d_in[2];
    const float* weight  = (const float*)d_in[3];
    const float* bias    = (const float*)d_in[4];
    float* out = (float*)d_out;

    const int B = in_sizes[2] / NP;

    char* ws = (char*)d_ws;
    size_t nd_bytes = (size_t)B * NP * 16 * 4;
    float* nd  = (float*)ws;
    int*   cnt = (int*)(ws + nd_bytes);
    int*   off = (int*)(ws + nd_bytes + (size_t)B * NSLAB * 4);
    size_t off_end = nd_bytes + (size_t)B * NSLAB * 4 + (size_t)B * (NSLAB + 1) * 4;
    size_t list_o  = (off_end + 255) & ~(size_t)255;
    int*   list = (int*)(ws + list_o);

    hipMemsetAsync(cnt, 0, (size_t)B * NSLAB * 4, stream);

    int totalE = B * NP * 16;
    k_nd<<<(totalE + 255) / 256, 256, 0, stream>>>(data, density, nd, totalE);
    int totalP = B * NP;
    k_hist<<<(totalP + 255) / 256, 256, 0, stream>>>(locs, cnt, totalP);
    k_scan<<<1, 64 * B, 0, stream>>>(cnt, off, B);
    k_rank<<<B * NSLAB, 256, 0, stream>>>(locs, off, list);
    k_main<<<B * NSLAB * MAXCHUNK, 256, 0, stream>>>(locs, nd, off, list, weight, bias, out);
}

// Round 3
// 110.717 us; speedup vs baseline: 1.4438x; 1.4438x over previous
//
#include <hip/hip_runtime.h>

#define NP 4096
#define NSLAB 64
#define ZSPAN 10        // slab width 1/64; |dz| <= 0.15 => +/-10 slabs covers it
#define EPS_K 1e-12f

// ---------- prep: z-slab histogram ----------
__global__ void k_hist(const float* __restrict__ locs, int* __restrict__ cnt, int totalP) {
    int i = blockIdx.x * 256 + threadIdx.x;
    if (i < totalP) {
        float z = locs[i * 3 + 2];
        int c = min(max((int)(z * 64.0f), 0), 63);
        atomicAdd(&cnt[(i >> 12) * NSLAB + c], 1);   // i>>12 == batch
    }
}

// ---------- prep: exclusive scan of 64 bins per batch ----------
__global__ void k_scan(const int* __restrict__ cnt, int* __restrict__ off, int B) {
    int lane = threadIdx.x & 63;
    int b = threadIdx.x >> 6;
    if (b >= B) return;
    int incl = cnt[b * NSLAB + lane];
    for (int d = 1; d < 64; d <<= 1) {
        int o = __shfl_up(incl, d, 64);
        if (lane >= d) incl += o;
    }
    off[b * (NSLAB + 1) + lane + 1] = incl;
    if (lane == 0) off[b * (NSLAB + 1)] = 0;
}

// ---------- prep: deterministic stable rank + scatter (block = one slab) ----------
__global__ __launch_bounds__(256) void k_rank(const float* __restrict__ locs,
                                              const int* __restrict__ off,
                                              int* __restrict__ list) {
    int b = blockIdx.x / NSLAB;
    int s = blockIdx.x % NSLAB;
    const float* lz = locs + (size_t)b * NP * 3;
    __shared__ int wtot[4];
    int base = off[b * (NSLAB + 1) + s];
    int running = 0;
    int tid = threadIdx.x, lane = tid & 63, w = tid >> 6;
    for (int chunk = 0; chunk < NP; chunk += 256) {
        int i = chunk + tid;
        float z = lz[i * 3 + 2];
        int c = min(max((int)(z * 64.0f), 0), 63);
        bool match = (c == s);
        unsigned long long m = __ballot(match);
        int pre = __popcll(m & ((1ull << lane) - 1ull));
        if (lane == 0) wtot[w] = (int)__popcll(m);
        __syncthreads();
        int bp = 0, tot = 0;
        for (int ww = 0; ww < 4; ++ww) { if (ww < w) bp += wtot[ww]; tot += wtot[ww]; }
        if (match) list[b * NP + base + running + bp + pre] = i;
        running += tot;
        __syncthreads();
    }
}

// ---------- prep: gather into sorted order; snd = data/density ----------
__global__ void k_reorder(const float* __restrict__ locs, const float* __restrict__ data,
                          const float* __restrict__ density, const int* __restrict__ list,
                          float4* __restrict__ slocs, float4* __restrict__ snd, int totalP) {
    int idx = blockIdx.x * 256 + threadIdx.x;    // over totalP*4
    if (idx >= totalP * 4) return;
    int pos = idx >> 2, q = idx & 3;
    int b = pos >> 12;
    int orig = list[pos];                         // in-batch index
    float invr = 1.0f / density[(b << 12) + orig];
    const float4 dv = ((const float4*)(data))[(((size_t)(b << 12) + orig) << 2) + q];
    float4 o4 = { dv.x * invr, dv.y * invr, dv.z * invr, dv.w * invr };
    snd[idx] = o4;                                // snd[pos*4 + q]
    if (q == 0) {
        const float* lp = locs + ((size_t)(b << 12) + orig) * 3;
        float4 s4 = { lp[0], lp[1], lp[2], __int_as_float(orig) };
        slocs[pos] = s4;
    }
}

// ---------- prep: weight transpose -> wT[k][o][c] ----------
__global__ void k_wt(const float* __restrict__ weight, float* __restrict__ wT) {
    int idx = blockIdx.x * 256 + threadIdx.x;
    if (idx >= 27 * 256) return;
    int k = idx >> 8, oc = idx & 255;
    wT[k * 256 + oc] = weight[oc * 27 + k];
}

// ---------- main: half-wave per particle, no LDS, no block sync ----------
__global__ __launch_bounds__(256) void k_main(
    const float4* __restrict__ slocs,  // [B*NP] sorted {x,y,z,orig}
    const float4* __restrict__ snd,    // [B*NP][4] sorted data/rho
    const int* __restrict__ off,       // [B][65]
    const float* __restrict__ wT,      // [27][16][16]
    const float* __restrict__ bias,
    float* __restrict__ out)
{
    const int bid  = blockIdx.x;
    const int b    = bid >> 9;          // 512 blocks per batch, all full
    const int blk  = bid & 511;
    const int tid  = threadIdx.x;
    const int p    = tid >> 5;
    const int lane = tid & 31;

    const float4* slb  = slocs + ((size_t)b << 12);
    const float4* sndb = snd   + ((size_t)b << 14);
    const int*    offb = off + b * (NSLAB + 1);

    const int P0 = blk << 3;
    const float4 me = slb[P0 + p];
    const int orig = __float_as_int(me.w);

    const int s_lo = min(max((int)(slb[P0].z     * 64.0f), 0), 63);
    const int s_hi = min(max((int)(slb[P0 + 7].z * 64.0f), 0), 63);
    const int jstart = offb[max(s_lo - ZSPAN, 0)];
    const int jend   = offb[min(s_hi + ZSPAN, NSLAB - 1) + 1];

    // this lane's kernel-cell center; lanes 27..31 never match
    float cx, cy, cz;
    {
        int kk = (lane < 27) ? lane : 13;
        cx = me.x + (float)(kk / 9       - 1) * 0.05f;
        cy = me.y + (float)((kk / 3) % 3 - 1) * 0.05f;
        cz = me.z + (float)(kk % 3       - 1) * 0.05f;
        if (lane >= 27) cx = 1e9f;
    }

    float kv[16];
#pragma unroll
    for (int c = 0; c < 16; ++c) kv[c] = 0.f;

    const int nsteps = (jend - jstart + 31) >> 5;
    int pos0 = jstart + lane;
    float4 lj = slb[min(pos0, jend - 1)];
    if (pos0 >= jend) lj.x = 1e9f;

    for (int st = 0; st < nsteps; ++st) {
        const int cbase = jstart + (st << 5);
        // register prefetch of next tile (clamped -> always a valid address)
        const int posn = cbase + 32 + lane;
        float4 ljn = slb[min(posn, jend - 1)];
        if (posn >= jend) ljn.x = 1e9f;

        // box prefilter: distance from j to i's dilated cell cube
        const float ex = fmaxf(fabsf(me.x - lj.x) - 0.05f, 0.f);
        const float ey = fmaxf(fabsf(me.y - lj.y) - 0.05f, 0.f);
        const float ez = fmaxf(fabsf(me.z - lj.z) - 0.05f, 0.f);
        const float bd2 = ex * ex + ey * ey + ez * ez;
        unsigned int mh = (unsigned int)(__ballot(bd2 < 0.01f) >> (tid & 32));

        while (mh) {
            const int bit = __ffs(mh) - 1;
            mh &= mh - 1;
            // nd loads: address depends only on bit -> issue immediately
            const float4* dp = sndb + (((size_t)(cbase + bit)) << 2);
            const float4 v0 = dp[0], v1 = dp[1], v2 = dp[2], v3 = dp[3];
            // neighbor coords from the scan register, no memory
            const float qx = __shfl(lj.x, bit, 32);
            const float qy = __shfl(lj.y, bit, 32);
            const float qz = __shfl(lj.z, bit, 32);
            const float dx = cx - qx, dy = cy - qy, dz = cz - qz;
            const float d2 = dx * dx + dy * dy + dz * dz;
            const float d = sqrtf(fmaxf(d2, EPS_K));
            float t1 = fmaxf(__builtin_fmaf(d, -10.f, 1.f), 0.f);  // max(1-d/R,0)
            const float w = t1 * t1 * t1;
            kv[ 0] = fmaf(w, v0.x, kv[ 0]);
            kv[ 1] = fmaf(w, v0.y, kv[ 1]);
            kv[ 2] = fmaf(w, v0.z, kv[ 2]);
            kv[ 3] = fmaf(w, v0.w, kv[ 3]);
            kv[ 4] = fmaf(w, v1.x, kv[ 4]);
            kv[ 5] = fmaf(w, v1.y, kv[ 5]);
            kv[ 6] = fmaf(w, v1.z, kv[ 6]);
            kv[ 7] = fmaf(w, v1.w, kv[ 7]);
            kv[ 8] = fmaf(w, v2.x, kv[ 8]);
            kv[ 9] = fmaf(w, v2.y, kv[ 9]);
            kv[10] = fmaf(w, v2.z, kv[10]);
            kv[11] = fmaf(w, v2.w, kv[11]);
            kv[12] = fmaf(w, v3.x, kv[12]);
            kv[13] = fmaf(w, v3.y, kv[13]);
            kv[14] = fmaf(w, v3.z, kv[14]);
            kv[15] = fmaf(w, v3.w, kv[15]);
        }
        lj = ljn;
    }

    // epilogue: out[o] = bias[o] + sum_k sum_c wT[k][o][c]*kv[k][c]
    const int kk = (lane < 27) ? lane : 26;     // idle lanes carry kv==0
    const float4* wrow = (const float4*)(wT + kk * 256);
    float res = 0.f;
#pragma unroll
    for (int o = 0; o < 16; ++o) {
        const float4 w0 = wrow[o * 4 + 0], w1 = wrow[o * 4 + 1];
        const float4 w2 = wrow[o * 4 + 2], w3 = wrow[o * 4 + 3];
        float acc = 0.f;
        acc = fmaf(w0.x, kv[ 0], acc); acc = fmaf(w0.y, kv[ 1], acc);
        acc = fmaf(w0.z, kv[ 2], acc); acc = fmaf(w0.w, kv[ 3], acc);
        acc = fmaf(w1.x, kv[ 4], acc); acc = fmaf(w1.y, kv[ 5], acc);
        acc = fmaf(w1.z, kv[ 6], acc); acc = fmaf(w1.w, kv[ 7], acc);
        acc = fmaf(w2.x, kv[ 8], acc); acc = fmaf(w2.y, kv[ 9], acc);
        acc = fmaf(w2.z, kv[10], acc); acc = fmaf(w2.w, kv[11], acc);
        acc = fmaf(w3.x, kv[12], acc); acc = fmaf(w3.y, kv[13], acc);
        acc = fmaf(w3.z, kv[14], acc); acc = fmaf(w3.w, kv[15], acc);
#pragma unroll
        for (int dsh = 16; dsh >= 1; dsh >>= 1)
            acc += __shfl_xor(acc, dsh, 32);
        if (lane == o) res = acc;
    }
    if (lane < 16)
        out[(((size_t)(b << 12)) + orig) * 16 + lane] = res + bias[lane];
}

extern "C" void kernel_launch(void* const* d_in, const int* in_sizes, int n_in,
                              void* d_out, int out_size, void* d_ws, size_t ws_size,
                              hipStream_t stream) {
    const float* locs    = (const float*)d_in[0];
    const float* data    = (const float*)d_in[1];
    const float* density = (const float*)d_in[2];
    const float* weight  = (const float*)d_in[3];
    const float* bias    = (const float*)d_in[4];
    float* out = (float*)d_out;

    const int B = in_sizes[2] / NP;
    const int totalP = B * NP;

    char* ws = (char*)d_ws;
    size_t o = 0;
    auto take = [&](size_t bytes) { size_t r = o; o = (o + bytes + 255) & ~(size_t)255; return r; };
    float4* slocs = (float4*)(ws + take((size_t)totalP * 16));
    float4* snd   = (float4*)(ws + take((size_t)totalP * 64));
    float*  wT    = (float*)(ws + take(27 * 256 * 4));
    int*    cnt   = (int*)(ws + take((size_t)B * NSLAB * 4));
    int*    off   = (int*)(ws + take((size_t)B * (NSLAB + 1) * 4));
    int*    list  = (int*)(ws + take((size_t)totalP * 4));

    hipMemsetAsync(cnt, 0, (size_t)B * NSLAB * 4, stream);
    k_hist<<<(totalP + 255) / 256, 256, 0, stream>>>(locs, cnt, totalP);
    k_scan<<<1, 64 * B, 0, stream>>>(cnt, off, B);
    k_rank<<<B * NSLAB, 256, 0, stream>>>(locs, off, list);
    k_reorder<<<(totalP * 4 + 255) / 256, 256, 0, stream>>>(locs, data, density, list, slocs, snd, totalP);
    k_wt<<<27, 256, 0, stream>>>(weight, wT);
    k_main<<<B * 512, 256, 0, stream>>>(slocs, snd, off, wT, bias, out);
}